// Round 10
// baseline (331.759 us; speedup 1.0000x reference)
//
#include <hip/hip_runtime.h>

// RGCN layer: out[i] = relu( x[i]@root + bias + sum_r mean_{j in N_r(i)} x[j]@W[r] )
//
// Two-phase (linearity) + SOURCE COMPACTION:
//   H rows [0,N) = bf16(x@root + bias); then per rel r one row per USED src:
//   bf16(x[src]@W[r]).  out[i] = relu( H[i] + sum_e (1/c) * H[hidx_e] )
// pk2 packs hidx(20b) | r(3b); per-(dst,rel) counts rebuilt in gather_out via
// wave-parallel ballot histogram. Byte used-flags w/ plain stores (R21: atomic
// RMW COUNT is the cost at the coherence point, not flag footprint).
//
// gemm_h v9b (R23): column-quarter tiling, HARDENED resubmission. R9's v9
// failed correctness (absmax 2.36, garbage-magnitude outputs) while the
// tiling math re-verifies on paper; the two unverifiable-by-inspection
// mechanisms were (a) inline-asm cvt_pk with "v" constraints on acc values
// that may live in AGPRs under the (256,4) 128-reg cap, (b) by-ref hinted
// resolve. v9b removes (a): epilogue packs via the proven C++ f32_to_bf16
// RNE (same function as XB/WT prep and the passing v6 epilogue). Tiling
// unchanged: 64 rows x 32 cols per tile, 36 pseudo-segs (seg x quarter),
// ~100 unified regs -> 4 waves/SIMD (2x the v8 TLP at 17% occupancy).
// PRE-COMMITTED: if this fails again, revert gemm_h+gather to the R8 kernel.
// H row layout: u32 index (q*16+l16) = { lo: col q*32+l16, hi: +16 };
// gather_out decodes c0 = 32*(lane>>4) + (lane&15).

#define D 128

typedef __attribute__((ext_vector_type(8))) short bf16x8;
typedef __attribute__((ext_vector_type(4))) float f32x4;
typedef __attribute__((ext_vector_type(4))) unsigned u32x4;

__device__ inline unsigned short f32_to_bf16(float f) {
    unsigned u = __float_as_uint(f);
    return (unsigned short)((u + 0x7FFF + ((u >> 16) & 1)) >> 16);   // RNE
}
__device__ inline float bf_lo(unsigned u) { return __uint_as_float(u << 16); }
__device__ inline float bf_hi(unsigned u) { return __uint_as_float(u & 0xFFFF0000u); }

// ---------------------------------------------------------------------------
// zero_ws: deg[n_nodes+1] and flags[4*nwords bytes] must be zero before hist.
// ---------------------------------------------------------------------------
__global__ __launch_bounds__(256) void zero_ws(
    int* __restrict__ deg, unsigned* __restrict__ flagsW, int n_nodes, int nwords)
{
    int i = blockIdx.x * 256 + threadIdx.x;
    if (i < n_nodes + 2) deg[i] = 0;
    if (i < nwords) flagsW[i] = 0u;
}

// ---------------------------------------------------------------------------
// prep_hist: fused. Blocks [0,hist_blocks) do the edge histogram (atomic
// latency-bound; start first): degree atomicAdd (returns rank-in-dst) +
// used-flag PLAIN byte store (benign same-value race, no RMW).
// Blocks [hist_blocks,..) do XB/WT conversion (streaming BW-bound).
// ---------------------------------------------------------------------------
__global__ __launch_bounds__(256) void prep_hist(
    const float* __restrict__ x, const float* __restrict__ W,
    const float* __restrict__ root,
    const int* __restrict__ edge_index, const int* __restrict__ edge_type,
    unsigned* __restrict__ XB, unsigned short* __restrict__ WT,
    int* __restrict__ deg, unsigned char* __restrict__ flags,
    int* __restrict__ erank,
    int nquads, int wt_total, int n_edges, int n_nodes, int n_rel,
    int hist_blocks)
{
    const int b = blockIdx.x;
    if (b < hist_blocks) {
        int e = b * 256 + threadIdx.x;
        if (e >= n_edges) return;
        int src = edge_index[e];
        int dst = edge_index[n_edges + e];
        int r   = edge_type[e];
        erank[e] = atomicAdd(&deg[dst], 1);          // degree + rank-in-dst
        flags[r * n_nodes + src] = 1;                // used flag (plain store)
        return;
    }
    int i = (b - hist_blocks) * 256 + threadIdx.x;
    if (i < nquads) {
        float4 v = ((const float4*)x)[i];
        unsigned w0 = (unsigned)f32_to_bf16(v.x) | ((unsigned)f32_to_bf16(v.y) << 16);
        unsigned w1 = (unsigned)f32_to_bf16(v.z) | ((unsigned)f32_to_bf16(v.w) << 16);
        ((uint2*)XB)[i] = make_uint2(w0, w1);
    }
    if (i < wt_total) {
        int seg = i >> 14, rem = i & 16383;
        int n = rem >> 7, k = rem & 127;
        float v = (seg == 0) ? root[k * D + n]
                             : W[(size_t)(seg - 1) * D * D + k * D + n];
        WT[i] = f32_to_bf16(v);
    }
}

// ---------------------------------------------------------------------------
// scanA2: fused block-level exclusive scans. Blocks [0,nAd): degree scan over
// deg[nd]. Blocks [nAd,..): flag-byte scan over flagsW[nw] words (bytes are
// 0/1, so popc(word) = count of set bytes).
// Consumers: Sd(i) = tmpd[i]+offsd[i>>10];  Sw(i) = tmpw[i]+offsw[i>>10].
// ---------------------------------------------------------------------------
__global__ __launch_bounds__(1024) void scanA2(
    const int* __restrict__ deg, const unsigned* __restrict__ flagsW,
    int* __restrict__ tmpd, int* __restrict__ partsd,
    int* __restrict__ tmpw, int* __restrict__ partsw,
    int nd, int nw, int nAd)
{
    __shared__ int buf[2][1024];
    const int tid = threadIdx.x;
    const bool isDeg = ((int)blockIdx.x < nAd);
    const int lb = isDeg ? blockIdx.x : (blockIdx.x - nAd);
    int i = lb * 1024 + tid;
    int v;
    if (isDeg) v = (i < nd) ? deg[i] : 0;
    else       v = (i < nw) ? (int)__popc(flagsW[i]) : 0;
    buf[0][tid] = v;
    __syncthreads();
    int pi = 0;
    for (int off = 1; off < 1024; off <<= 1) {
        int t = buf[pi][tid] + ((tid >= off) ? buf[pi][tid - off] : 0);
        buf[1 - pi][tid] = t;
        pi = 1 - pi;
        __syncthreads();
    }
    if (isDeg) {
        if (i < nd) tmpd[i] = buf[pi][tid] - v;
        if (tid == 1023) partsd[lb] = buf[pi][1023];
    } else {
        if (i < nw) tmpw[i] = buf[pi][tid] - v;
        if (tid == 1023) partsw[lb] = buf[pi][1023];
    }
}

// scanB2: block 0 scans degree partials -> offsd; block 1 scans word partials
// -> offsw + totw (total compact rows).
__global__ __launch_bounds__(1024) void scanB2(
    const int* __restrict__ partsd, const int* __restrict__ partsw,
    int* __restrict__ offsd, int* __restrict__ offsw,
    int* __restrict__ totw, int npd, int npw)
{
    __shared__ int buf[2][1024];
    const int t = threadIdx.x;
    const bool w = (blockIdx.x == 1);
    const int np = w ? npw : npd;
    int v = (t < np) ? (w ? partsw[t] : partsd[t]) : 0;
    buf[0][t] = v;
    __syncthreads();
    int pi = 0;
    for (int off = 1; off < 1024; off <<= 1) {
        int s = buf[pi][t] + ((t >= off) ? buf[pi][t - off] : 0);
        buf[1 - pi][t] = s;
        pi = 1 - pi;
        __syncthreads();
    }
    if (t < np) { if (w) offsw[t] = buf[pi][t] - v; else offsd[t] = buf[pi][t] - v; }
    if (w && t == 0) totw[0] = buf[pi][1023];
}

// ---------------------------------------------------------------------------
// edge_bin: CSR-place each edge at Sd(dst)+rank (no atomics); pack hidx|r;
// compact index from the word scan + intra-word byte popcount (flags/tmpw/
// offsw are ~1.6MB total -> L2-hot). csrc same-value races: benign.
// ---------------------------------------------------------------------------
__global__ __launch_bounds__(256) void edge_bin(
    const int* __restrict__ edge_index, const int* __restrict__ edge_type,
    const int* __restrict__ tmpd, const int* __restrict__ offsd,
    const int* __restrict__ tmpw, const int* __restrict__ offsw,
    const unsigned* __restrict__ flagsW, const int* __restrict__ erank,
    unsigned* __restrict__ pk2, int* __restrict__ csrc,
    int n_edges, int n_nodes, int n_rel)
{
    int e = blockIdx.x * 256 + threadIdx.x;
    if (e >= n_edges) return;
    int src = edge_index[e];
    int dst = edge_index[n_edges + e];
    int r   = edge_type[e];
    int pos = tmpd[dst] + offsd[dst >> 10] + erank[e];
    int gi  = r * n_nodes + src;
    int w   = gi >> 2;
    unsigned bw = flagsW[w];
    int cidx = tmpw[w] + offsw[w >> 10]
             + (int)__popc(bw & ((1u << (8 * (gi & 3))) - 1u));
    int hidx = n_nodes + cidx;                        // < 2^20
    pk2[pos] = (unsigned)hidx | ((unsigned)r << 20);
    csrc[cidx] = src;                                 // same-value race: benign
}

// ---------------------------------------------------------------------------
// Phase 1 v9b: flat-balanced H GEMM over 36 pseudo-segments (seg x quarter),
// 64 rows x 32 cols per tile per block, nt=2. ~100 unified regs ->
// __launch_bounds__(256,4) -> 4 waves/SIMD. 3-stage pipeline (v7-proven
// structure): tile t computes while XB(t+1) loads (node resident from one
// iteration ago) and csrc(t+2) loads. B-frags (32 regs) reloaded only at
// pseudo-seg boundaries. Epilogue: C++ RNE pack (no inline asm). grid 1024.
// ---------------------------------------------------------------------------
__global__ __launch_bounds__(256, 4) void gemm_h(
    const unsigned* __restrict__ XB, const unsigned short* __restrict__ WT,
    const float* __restrict__ bias, const int* __restrict__ csrc,
    const int* __restrict__ tmpw, const int* __restrict__ offsw,
    const int* __restrict__ totw, unsigned short* __restrict__ H,
    int n_nodes, int n_rel)
{
    __shared__ int s_end[36];    // cumulative flat-tile end per pseudo-seg
    __shared__ int s_cnt[36];    // row count per pseudo-seg
    __shared__ int s_S0[36];     // csrc base per pseudo-seg
    __shared__ int s_base[36];   // H base row per pseudo-seg

    const int tid  = threadIdx.x;
    const int wave = tid >> 6;
    const int lane = tid & 63;
    const int l16  = lane & 15;
    const int quad = lane >> 4;
    const int row_off = wave * 16 + l16;
    const int cq8  = quad * 8;
    const int npseg = 4 * (n_rel + 1);

    // pseudo-seg table: 36 threads in parallel, then prefix by thread 0.
    if (tid < npseg) {
        const int s = tid >> 2;
        int cnt, S0 = 0, base;
        if (s == 0) { cnt = n_nodes; base = 0; }
        else {
            int r = s - 1;
            const int wpr = n_nodes >> 2;            // flag words per rel
            int w0 = r * wpr;
            S0 = tmpw[w0] + offsw[w0 >> 10];
            int S1;
            if (r == n_rel - 1) S1 = totw[0];
            else { int w1 = w0 + wpr; S1 = tmpw[w1] + offsw[w1 >> 10]; }
            cnt = S1 - S0;
            base = n_nodes + S0;
        }
        s_cnt[tid] = cnt; s_S0[tid] = S0; s_base[tid] = base;
        s_end[tid] = (cnt + 63) >> 6;            // tiles (pre-prefix)
    }
    __syncthreads();
    if (tid == 0) {
        int acc = 0;
        for (int i = 0; i < npseg; ++i) { acc += s_end[i]; s_end[i] = acc; }
    }
    __syncthreads();

    const int nflat = s_end[npseg - 1];
    const int chunk = (nflat + gridDim.x - 1) / gridDim.x;
    const int ft0 = blockIdx.x * chunk;
    int ft1 = ft0 + chunk; if (ft1 > nflat) ft1 = nflat;
    if (ft0 >= ft1) return;

    // fresh-scan resolve (v8 semantics; O(36) LDS reads, few calls matter).
    auto resolve = [&](int ft, int& ps, int& lt) {
        int s = 0;
        while (ft >= s_end[s]) ++s;
        ps = s;
        lt = ft - (s ? s_end[s - 1] : 0);
    };
    auto load_node = [&](int ps, int lt) -> int {
        int lr = lt * 64 + row_off;
        if (lr >= s_cnt[ps]) return 0;
        return (ps < 4) ? lr : csrc[s_S0[ps] + lr];
    };
    auto load_af = [&](int ps, int lt, int node, bf16x8* fr) {
        int lr = lt * 64 + row_off;
        bool v = (lr < s_cnt[ps]);
        const unsigned short* xr = (const unsigned short*)XB + (size_t)node * D + cq8;
#pragma unroll
        for (int kc = 0; kc < 4; ++kc)
            fr[kc] = v ? *(const bf16x8*)(xr + kc * 32)
                       : (bf16x8){0, 0, 0, 0, 0, 0, 0, 0};
    };

    bf16x8 bfr[2][4];
    float bv[2];
    int cur_ps = -1;

    // ---- pipeline prologue ----
    int psA, ltA;
    resolve(ft0, psA, ltA);
    bf16x8 af[4];
    {
        int nodeA = load_node(psA, ltA);
        load_af(psA, ltA, nodeA, af);
    }
    int psB = psA, ltB = 0, nodeB = 0;
    if (ft0 + 1 < ft1) {
        resolve(ft0 + 1, psB, ltB);
        nodeB = load_node(psB, ltB);
    }

    for (int ft = ft0; ft < ft1; ++ft) {
        const int ps = psA, lt = ltA;
        const bool haveN  = (ft + 1 < ft1);
        const bool haveN2 = (ft + 2 < ft1);

        // stage 3: issue csrc for t+2 (completes during next iteration)
        int psC = 0, ltC = 0, nodeC = 0;
        if (haveN2) {
            resolve(ft + 2, psC, ltC);
            nodeC = load_node(psC, ltC);
        }

        // stage 2: issue XB gathers for t+1 (nodeB loaded one iteration ago)
        bf16x8 afn[4];
        if (haveN) load_af(psB, ltB, nodeB, afn);

        // (re)load B-frags + bias at pseudo-seg boundary (<=2 per block)
        if (ps != cur_ps) {
            const int s = ps >> 2, q = ps & 3;
            const unsigned short* Wseg = WT + (size_t)s * D * D;
#pragma unroll
            for (int nt = 0; nt < 2; ++nt) {
                const int n = q * 32 + nt * 16 + l16;
                const unsigned short* bp = Wseg + (size_t)n * D + cq8;
#pragma unroll
                for (int kc = 0; kc < 4; ++kc)
                    bfr[nt][kc] = *(const bf16x8*)(bp + kc * 32);
                bv[nt] = (s == 0) ? bias[n] : 0.f;
            }
            cur_ps = ps;
        }

        // stage 1: compute tile t (bias folded into MFMA C-in; same f32 math)
        f32x4 acc[2];
#pragma unroll
        for (int nt = 0; nt < 2; ++nt) {
            acc[nt] = (f32x4){bv[nt], bv[nt], bv[nt], bv[nt]};
#pragma unroll
            for (int kc = 0; kc < 4; ++kc)
                acc[nt] = __builtin_amdgcn_mfma_f32_16x16x32_bf16(
                    af[kc], bfr[nt][kc], acc[nt], 0, 0, 0);
        }

        // Epilogue: C++ RNE pack (col q*32+l16, +16) -> u32, one dword per
        // owned row. 4 quads x 64B row segments per instruction.
        {
            const int q = ps & 3;
            const int rbase = lt * 64 + wave * 16 + quad * 4;
            unsigned short* Hrow =
                H + (size_t)(s_base[ps] + rbase) * D + q * 32 + l16 * 2;
#pragma unroll
            for (int reg = 0; reg < 4; ++reg) {
                if (rbase + reg < s_cnt[ps]) {
                    unsigned lo = f32_to_bf16(acc[0][reg]);
                    unsigned hi = f32_to_bf16(acc[1][reg]);
                    *(unsigned*)(Hrow + (size_t)reg * D) = lo | (hi << 16);
                }
            }
        }

        // rotate pipeline state
        if (haveN) {
            psA = psB; ltA = ltB;
#pragma unroll
            for (int kc = 0; kc < 4; ++kc) af[kc] = afn[kc];
        }
        if (haveN2) { psB = psC; ltB = ltC; nodeB = nodeC; }
    }
}

// ---------------------------------------------------------------------------
// Phase 2: one wave per dst node; dst made explicitly wave-uniform so
// pk2/bounds go through scalar loads; per-lane work = H load + 2 unpack +
// 2 FMA per edge. Per-(dst,rel) counts via wave-parallel ballot histogram
// (one coalesced pk2 vector load, 8 ballots -> packed 8-bit fields in two
// u32s; scalar fallback for degree > 64). 1/c via v_rcp (~1 ulp).
// H columns (v9 layout): lane j's u32 holds cols c0 = 32*(j>>4) + (j&15)
// and c0+16 -> two dword stores at the end.
// ---------------------------------------------------------------------------
__global__ __launch_bounds__(256) void gather_out(
    const unsigned short* __restrict__ H, const unsigned* __restrict__ pk2,
    const int* __restrict__ tmpd, const int* __restrict__ offsd,
    float* __restrict__ out, int n_nodes)
{
    int dst = (blockIdx.x * 256 + threadIdx.x) >> 6;
    const int lane = threadIdx.x & 63;
    if (dst >= n_nodes) return;
    dst = __builtin_amdgcn_readfirstlane(dst);   // wave-uniform by construction

    const unsigned* HH = (const unsigned*)H;
    unsigned u0 = HH[(size_t)dst * 64 + lane];   // root+bias row
    float a0 = bf_lo(u0), a1 = bf_hi(u0);

    const int e0 = tmpd[dst] + offsd[dst >> 10];
    const int e1 = tmpd[dst + 1] + offsd[(dst + 1) >> 10];
    const int d  = e1 - e0;

    // per-rel counts (8x 8-bit fields in two u32s)
    unsigned acc0 = 0, acc1 = 0;
    if (d <= 64) {
        const bool valid = lane < d;
        unsigned p = valid ? pk2[e0 + lane] : 0u;
        unsigned r = (p >> 20) & 7u;
#pragma unroll
        for (int rr = 0; rr < 8; ++rr) {
            unsigned long long m = __ballot(valid && (r == (unsigned)rr));
            unsigned cnt = (unsigned)__popcll(m);
            if (rr < 4) acc0 |= cnt << (rr * 8);
            else        acc1 |= cnt << ((rr - 4) * 8);
        }
    } else {
        for (int e = e0; e < e1; ++e) {
            unsigned p = pk2[e];
            unsigned r = (p >> 20) & 7u;
            unsigned add = 1u << ((r & 3u) * 8u);
            if (r & 4u) acc1 += add; else acc0 += add;
        }
    }

    for (int base = e0; base < e1; base += 8) {
        float al[8];
        const unsigned* hp[8];
#pragma unroll
        for (int j = 0; j < 8; ++j) {
            int e = base + j;
            bool ok = (e < e1);
            unsigned p = ok ? pk2[e] : 0u;       // uniform address -> s_load
            unsigned r = (p >> 20) & 7u;
            unsigned cnt = (((r & 4u) ? acc1 : acc0) >> ((r & 3u) * 8u)) & 255u;
            al[j] = ok ? __builtin_amdgcn_rcpf((float)cnt) : 0.f;
            hp[j] = HH + (size_t)(p & 0xFFFFFu) * 64;
        }
        unsigned hv[8];
#pragma unroll
        for (int j = 0; j < 8; ++j) hv[j] = hp[j][lane];
#pragma unroll
        for (int j = 0; j < 8; ++j) {
            a0 += al[j] * bf_lo(hv[j]);
            a1 += al[j] * bf_hi(hv[j]);
        }
    }

    const int c0 = ((lane >> 4) << 5) + (lane & 15);   // v9 layout decode
    float* orow = out + (size_t)dst * D;
    orow[c0]      = fmaxf(a0, 0.f);
    orow[c0 + 16] = fmaxf(a1, 0.f);
}

extern "C" void kernel_launch(void* const* d_in, const int* in_sizes, int n_in,
                              void* d_out, int out_size, void* d_ws, size_t ws_size,
                              hipStream_t stream) {
    const float* x          = (const float*)d_in[0];
    const int*   edge_index = (const int*)d_in[1];
    const int*   edge_type  = (const int*)d_in[2];
    const float* W          = (const float*)d_in[3];
    const float* root       = (const float*)d_in[4];
    const float* bias       = (const float*)d_in[5];
    float* out = (float*)d_out;

    const int n_nodes = in_sizes[0] / D;          // 100000 (assumed %4==0)
    const int n_edges = in_sizes[2];              // 600000
    const int n_rel   = in_sizes[3] / (D * D);    // 8
    const int nsegs   = n_rel + 1;
    const int nwords  = (n_rel * n_nodes) >> 2;   // 200000 (800KB byte flags)

    // ws layout (worst-case compact rows = n_rel*n_nodes)
    char* p = (char*)d_ws;
    auto alloc = [&](size_t bytes) {
        char* q = p; p += (bytes + 255) & ~(size_t)255; return q;
    };
    int* deg    = (int*)alloc((size_t)(n_nodes + 2) * 4);
    int* tmpd   = (int*)alloc((size_t)(n_nodes + 2) * 4);
    unsigned* flagsW = (unsigned*)alloc((size_t)nwords * 4);
    int* tmpw   = (int*)alloc((size_t)(nwords + 1) * 4);
    int* partsd = (int*)alloc(4096);
    int* partsw = (int*)alloc(4096);
    int* offsd  = (int*)alloc(4096);
    int* offsw  = (int*)alloc(4096);
    int* totw   = (int*)alloc(256);
    int* erank  = (int*)alloc((size_t)n_edges * 4);
    unsigned* pk2 = (unsigned*)alloc((size_t)n_edges * 4);
    unsigned* XB  = (unsigned*)alloc((size_t)n_nodes * (D / 2) * 4);
    unsigned short* WT = (unsigned short*)alloc((size_t)nsegs * D * D * 2);
    int* csrc   = (int*)alloc((size_t)n_edges * 4);
    unsigned short* H = (unsigned short*)p;       // worst (n_nodes + n_edges) rows

    const int nquads   = n_nodes * (D / 4);
    const int wt_total = nsegs * D * D;
    int conv_n = nquads;
    if (wt_total > conv_n) conv_n = wt_total;

    const int egrid = (n_edges + 255) / 256;
    const int conv_blocks = (conv_n + 255) / 256;
    const int nAd = (n_nodes + 1 + 1023) / 1024;  // 98
    const int nAw = (nwords + 1023) / 1024;       // 196

    int zero_n = n_nodes + 2;
    if (nwords > zero_n) zero_n = nwords;

    zero_ws<<<(zero_n + 255) / 256, 256, 0, stream>>>(
        deg, flagsW, n_nodes, nwords);
    prep_hist<<<egrid + conv_blocks, 256, 0, stream>>>(
        x, W, root, edge_index, edge_type, XB, WT, deg,
        (unsigned char*)flagsW, erank,
        nquads, wt_total, n_edges, n_nodes, n_rel, egrid);
    scanA2<<<nAd + nAw, 1024, 0, stream>>>(
        deg, flagsW, tmpd, partsd, tmpw, partsw, n_nodes + 1, nwords, nAd);
    scanB2<<<2, 1024, 0, stream>>>(partsd, partsw, offsd, offsw, totw, nAd, nAw);
    edge_bin<<<egrid, 256, 0, stream>>>(
        edge_index, edge_type, tmpd, offsd, tmpw, offsw, flagsW, erank,
        pk2, csrc, n_edges, n_nodes, n_rel);
    gemm_h<<<1024, 256, 0, stream>>>(
        XB, WT, bias, csrc, tmpw, offsw, totw, H, n_nodes, n_rel);
    gather_out<<<(n_nodes + 3) / 4, 256, 0, stream>>>(
        H, pk2, tmpd, offsd, out, n_nodes);
}

// Round 11
// 257.840 us; speedup vs baseline: 1.2867x; 1.2867x over previous
//
#include <hip/hip_runtime.h>

// RGCN layer: out[i] = relu( x[i]@root + bias + sum_r mean_{j in N_r(i)} x[j]@W[r] )
//
// Two-phase (linearity) + SOURCE COMPACTION:
//   H rows [0,N) = bf16(x@root + bias); then per rel r one row per USED src:
//   bf16(x[src]@W[r]).  out[i] = relu( H[i] + sum_e (1/c) * H[hidx_e] )
// pk2 packs hidx(20b) | r(3b); per-(dst,rel) counts rebuilt in gather_out via
// wave-parallel ballot histogram. Byte used-flags w/ plain stores (R21: atomic
// RMW COUNT is the cost at the coherence point, not flag footprint).
//
// R24: REVERT gemm_h+gather_out to the R8-proven v7-pipeline versions.
// v9/v9b (column-quarter tiling for occupancy) is CLOSED: R10 counters show
// FETCH 65.9 -> 250MB (4 blocks re-gather the same A-rows; per-XCD L2 4MB
// can't hold XB 25.6MB; L3 service for this pattern runs ~3TB/s) -> kernel
// went traffic-bound, 52 -> 127us. Any k-way column split multiplies
// A-gather traffic by k; halves compute to ~75us. R8's 201MB @ 3.87TB/s is
// ~the gather-pattern BW ceiling. Also learned (R9 vs R10): inline-asm
// v_cvt_pk with "v" constraints breaks when regalloc puts acc in AGPRs --
// use C++ RNE or builtins only.
//
// gemm_h (v7 pipeline, proven 52us): 128-col tile, nt=8, bfr in AGPRs,
// 128 VGPR + 128 AGPR = exactly the 2-waves/SIMD budget -- do NOT add live
// registers. grid 512 (16 iters/block, 2 blocks/CU), segment table by 9
// threads in parallel, csrc dist-2 / XB dist-1 prefetch, cvt_pk-free
// epilogue... (asm cvt_pk OK here: at (256,2) acc stays in VGPRs -- kept
// from R8 verbatim since it passed twice).
// H row layout: u32 index (l16*4+p) = { lo: col 32p+l16, hi: +16 };
// gather_out decodes c0 = 32*(lane&3) + (lane>>2).

#define D 128

typedef __attribute__((ext_vector_type(8))) short bf16x8;
typedef __attribute__((ext_vector_type(4))) float f32x4;
typedef __attribute__((ext_vector_type(4))) unsigned u32x4;

__device__ inline unsigned short f32_to_bf16(float f) {
    unsigned u = __float_as_uint(f);
    return (unsigned short)((u + 0x7FFF + ((u >> 16) & 1)) >> 16);   // RNE
}
__device__ inline float bf_lo(unsigned u) { return __uint_as_float(u << 16); }
__device__ inline float bf_hi(unsigned u) { return __uint_as_float(u & 0xFFFF0000u); }

// ---------------------------------------------------------------------------
// zero_ws: deg[n_nodes+1] and flags[4*nwords bytes] must be zero before hist.
// ---------------------------------------------------------------------------
__global__ __launch_bounds__(256) void zero_ws(
    int* __restrict__ deg, unsigned* __restrict__ flagsW, int n_nodes, int nwords)
{
    int i = blockIdx.x * 256 + threadIdx.x;
    if (i < n_nodes + 2) deg[i] = 0;
    if (i < nwords) flagsW[i] = 0u;
}

// ---------------------------------------------------------------------------
// prep_hist: fused. Blocks [0,hist_blocks) do the edge histogram (atomic
// latency-bound; start first): degree atomicAdd (returns rank-in-dst) +
// used-flag PLAIN byte store (benign same-value race, no RMW).
// Blocks [hist_blocks,..) do XB/WT conversion (streaming BW-bound).
// ---------------------------------------------------------------------------
__global__ __launch_bounds__(256) void prep_hist(
    const float* __restrict__ x, const float* __restrict__ W,
    const float* __restrict__ root,
    const int* __restrict__ edge_index, const int* __restrict__ edge_type,
    unsigned* __restrict__ XB, unsigned short* __restrict__ WT,
    int* __restrict__ deg, unsigned char* __restrict__ flags,
    int* __restrict__ erank,
    int nquads, int wt_total, int n_edges, int n_nodes, int n_rel,
    int hist_blocks)
{
    const int b = blockIdx.x;
    if (b < hist_blocks) {
        int e = b * 256 + threadIdx.x;
        if (e >= n_edges) return;
        int src = edge_index[e];
        int dst = edge_index[n_edges + e];
        int r   = edge_type[e];
        erank[e] = atomicAdd(&deg[dst], 1);          // degree + rank-in-dst
        flags[r * n_nodes + src] = 1;                // used flag (plain store)
        return;
    }
    int i = (b - hist_blocks) * 256 + threadIdx.x;
    if (i < nquads) {
        float4 v = ((const float4*)x)[i];
        unsigned w0 = (unsigned)f32_to_bf16(v.x) | ((unsigned)f32_to_bf16(v.y) << 16);
        unsigned w1 = (unsigned)f32_to_bf16(v.z) | ((unsigned)f32_to_bf16(v.w) << 16);
        ((uint2*)XB)[i] = make_uint2(w0, w1);
    }
    if (i < wt_total) {
        int seg = i >> 14, rem = i & 16383;
        int n = rem >> 7, k = rem & 127;
        float v = (seg == 0) ? root[k * D + n]
                             : W[(size_t)(seg - 1) * D * D + k * D + n];
        WT[i] = f32_to_bf16(v);
    }
}

// ---------------------------------------------------------------------------
// scanA2: fused block-level exclusive scans. Blocks [0,nAd): degree scan over
// deg[nd]. Blocks [nAd,..): flag-byte scan over flagsW[nw] words (bytes are
// 0/1, so popc(word) = count of set bytes).
// Consumers: Sd(i) = tmpd[i]+offsd[i>>10];  Sw(i) = tmpw[i]+offsw[i>>10].
// ---------------------------------------------------------------------------
__global__ __launch_bounds__(1024) void scanA2(
    const int* __restrict__ deg, const unsigned* __restrict__ flagsW,
    int* __restrict__ tmpd, int* __restrict__ partsd,
    int* __restrict__ tmpw, int* __restrict__ partsw,
    int nd, int nw, int nAd)
{
    __shared__ int buf[2][1024];
    const int tid = threadIdx.x;
    const bool isDeg = ((int)blockIdx.x < nAd);
    const int lb = isDeg ? blockIdx.x : (blockIdx.x - nAd);
    int i = lb * 1024 + tid;
    int v;
    if (isDeg) v = (i < nd) ? deg[i] : 0;
    else       v = (i < nw) ? (int)__popc(flagsW[i]) : 0;
    buf[0][tid] = v;
    __syncthreads();
    int pi = 0;
    for (int off = 1; off < 1024; off <<= 1) {
        int t = buf[pi][tid] + ((tid >= off) ? buf[pi][tid - off] : 0);
        buf[1 - pi][tid] = t;
        pi = 1 - pi;
        __syncthreads();
    }
    if (isDeg) {
        if (i < nd) tmpd[i] = buf[pi][tid] - v;
        if (tid == 1023) partsd[lb] = buf[pi][1023];
    } else {
        if (i < nw) tmpw[i] = buf[pi][tid] - v;
        if (tid == 1023) partsw[lb] = buf[pi][1023];
    }
}

// scanB2: block 0 scans degree partials -> offsd; block 1 scans word partials
// -> offsw + totw (total compact rows).
__global__ __launch_bounds__(1024) void scanB2(
    const int* __restrict__ partsd, const int* __restrict__ partsw,
    int* __restrict__ offsd, int* __restrict__ offsw,
    int* __restrict__ totw, int npd, int npw)
{
    __shared__ int buf[2][1024];
    const int t = threadIdx.x;
    const bool w = (blockIdx.x == 1);
    const int np = w ? npw : npd;
    int v = (t < np) ? (w ? partsw[t] : partsd[t]) : 0;
    buf[0][t] = v;
    __syncthreads();
    int pi = 0;
    for (int off = 1; off < 1024; off <<= 1) {
        int s = buf[pi][t] + ((t >= off) ? buf[pi][t - off] : 0);
        buf[1 - pi][t] = s;
        pi = 1 - pi;
        __syncthreads();
    }
    if (t < np) { if (w) offsw[t] = buf[pi][t] - v; else offsd[t] = buf[pi][t] - v; }
    if (w && t == 0) totw[0] = buf[pi][1023];
}

// ---------------------------------------------------------------------------
// edge_bin: CSR-place each edge at Sd(dst)+rank (no atomics); pack hidx|r;
// compact index from the word scan + intra-word byte popcount (flags/tmpw/
// offsw are ~1.6MB total -> L2-hot). csrc same-value races: benign.
// ---------------------------------------------------------------------------
__global__ __launch_bounds__(256) void edge_bin(
    const int* __restrict__ edge_index, const int* __restrict__ edge_type,
    const int* __restrict__ tmpd, const int* __restrict__ offsd,
    const int* __restrict__ tmpw, const int* __restrict__ offsw,
    const unsigned* __restrict__ flagsW, const int* __restrict__ erank,
    unsigned* __restrict__ pk2, int* __restrict__ csrc,
    int n_edges, int n_nodes, int n_rel)
{
    int e = blockIdx.x * 256 + threadIdx.x;
    if (e >= n_edges) return;
    int src = edge_index[e];
    int dst = edge_index[n_edges + e];
    int r   = edge_type[e];
    int pos = tmpd[dst] + offsd[dst >> 10] + erank[e];
    int gi  = r * n_nodes + src;
    int w   = gi >> 2;
    unsigned bw = flagsW[w];
    int cidx = tmpw[w] + offsw[w >> 10]
             + (int)__popc(bw & ((1u << (8 * (gi & 3))) - 1u));
    int hidx = n_nodes + cidx;                        // < 2^20
    pk2[pos] = (unsigned)hidx | ((unsigned)r << 20);
    csrc[cidx] = src;                                 // same-value race: benign
}

// ---------------------------------------------------------------------------
// Phase 1 (v7 pipeline, proven): flat-balanced H GEMM, register->global
// epilogue, 3-stage software pipeline: tile t computes while XB(t+1) loads
// (node index already resident from one iteration ago) and csrc(t+2) loads.
// grid (512, 1) -- 16 iters/block, 2 resident blocks/CU. Segment table built
// by 9 threads in parallel from the word scan. B-frags register/AGPR
// resident, reloaded only at segment boundaries (<=2 per block). 128 VGPR +
// ~128 AGPR = exactly the 2-waves/SIMD budget -- do NOT add live registers.
// ---------------------------------------------------------------------------
__global__ __launch_bounds__(256, 2) void gemm_h(
    const unsigned* __restrict__ XB, const unsigned short* __restrict__ WT,
    const float* __restrict__ bias, const int* __restrict__ csrc,
    const int* __restrict__ tmpw, const int* __restrict__ offsw,
    const int* __restrict__ totw, unsigned short* __restrict__ H,
    int n_nodes, int n_rel)
{
    __shared__ int s_end[9];     // cumulative flat-tile end per seg
    __shared__ int s_cnt[9];     // row count per seg
    __shared__ int s_S0[9];      // csrc base per seg
    __shared__ int s_base[9];    // H base row per seg

    const int tid  = threadIdx.x;
    const int wave = tid >> 6;
    const int lane = tid & 63;
    const int l16  = lane & 15;
    const int quad = lane >> 4;
    const int row_off = wave * 16 + l16;
    const int cq8  = quad * 8;

    // segment table: 9 threads in parallel, then 9-element prefix by thread 0.
    if (tid <= n_rel) {
        const int s = tid;
        int cnt, S0 = 0, base;
        if (s == 0) { cnt = n_nodes; base = 0; }
        else {
            int r = s - 1;
            const int wpr = n_nodes >> 2;            // flag words per rel
            int w0 = r * wpr;
            S0 = tmpw[w0] + offsw[w0 >> 10];
            int S1;
            if (r == n_rel - 1) S1 = totw[0];
            else { int w1 = w0 + wpr; S1 = tmpw[w1] + offsw[w1 >> 10]; }
            cnt = S1 - S0;
            base = n_nodes + S0;
        }
        s_cnt[s] = cnt; s_S0[s] = S0; s_base[s] = base;
        s_end[s] = (cnt + 63) >> 6;              // per-seg tile count (pre-prefix)
    }
    __syncthreads();
    if (tid == 0) {
        int acc = 0;
        for (int s = 0; s <= n_rel; ++s) { acc += s_end[s]; s_end[s] = acc; }
    }
    __syncthreads();

    const int nflat = s_end[n_rel];
    const int chunk = (nflat + gridDim.x - 1) / gridDim.x;
    const int ft0 = blockIdx.x * chunk;
    int ft1 = ft0 + chunk; if (ft1 > nflat) ft1 = nflat;
    if (ft0 >= ft1) return;

    auto resolve = [&](int ft, int& seg, int& lt) {
        int s = 0;
        while (ft >= s_end[s]) ++s;
        seg = s;
        lt = ft - (s ? s_end[s - 1] : 0);
    };
    auto load_node = [&](int seg, int lt) -> int {
        int lr = lt * 64 + row_off;
        if (lr >= s_cnt[seg]) return 0;
        return (seg == 0) ? lr : csrc[s_S0[seg] + lr];
    };
    auto load_af = [&](int seg, int lt, int node, bf16x8* fr) {
        int lr = lt * 64 + row_off;
        bool v = (lr < s_cnt[seg]);
        const unsigned short* xr = (const unsigned short*)XB + (size_t)node * D + cq8;
#pragma unroll
        for (int kc = 0; kc < 4; ++kc)
            fr[kc] = v ? *(const bf16x8*)(xr + kc * 32)
                       : (bf16x8){0, 0, 0, 0, 0, 0, 0, 0};
    };

    bf16x8 bfr[8][4];
    float bv[8];
    int cur_seg = -1;

    // ---- pipeline prologue ----
    int segA, ltA;
    resolve(ft0, segA, ltA);
    bf16x8 af[4];
    {
        int nodeA = load_node(segA, ltA);
        load_af(segA, ltA, nodeA, af);
    }
    int segB = 0, ltB = 0, nodeB = 0;
    if (ft0 + 1 < ft1) {
        resolve(ft0 + 1, segB, ltB);
        nodeB = load_node(segB, ltB);
    }

    for (int ft = ft0; ft < ft1; ++ft) {
        const int seg = segA, lt = ltA;
        const bool haveN  = (ft + 1 < ft1);
        const bool haveN2 = (ft + 2 < ft1);

        // stage 3: issue csrc for t+2 (completes during next iteration)
        int segC = 0, ltC = 0, nodeC = 0;
        if (haveN2) {
            resolve(ft + 2, segC, ltC);
            nodeC = load_node(segC, ltC);
        }

        // stage 2: issue XB gathers for t+1 (nodeB loaded one iteration ago)
        bf16x8 afn[4];
        if (haveN) load_af(segB, ltB, nodeB, afn);

        // (re)load B-frags + bias at segment boundary (<=2 per block)
        if (seg != cur_seg) {
            const unsigned short* Wseg = WT + (size_t)seg * D * D;
#pragma unroll
            for (int nt = 0; nt < 8; ++nt) {
                const unsigned short* bp = Wseg + (size_t)(nt * 16 + l16) * D + cq8;
#pragma unroll
                for (int kc = 0; kc < 4; ++kc)
                    bfr[nt][kc] = *(const bf16x8*)(bp + kc * 32);
                bv[nt] = (seg == 0) ? bias[nt * 16 + l16] : 0.f;
            }
            cur_seg = seg;
        }

        // stage 1: compute tile t (bias folded into MFMA C-in; same f32 math)
        f32x4 acc[8];
#pragma unroll
        for (int nt = 0; nt < 8; ++nt) {
            acc[nt] = (f32x4){bv[nt], bv[nt], bv[nt], bv[nt]};
#pragma unroll
            for (int kc = 0; kc < 4; ++kc)
                acc[nt] = __builtin_amdgcn_mfma_f32_16x16x32_bf16(
                    af[kc], bfr[nt][kc], acc[nt], 0, 0, 0);
        }

        // Epilogue: hardware RNE pack (col 32p+l16, col 32p+l16+16) -> u32,
        // one dwordx4 per owned row. Coalesces as 4x256B segments per inst.
        // (inline-asm cvt_pk is safe HERE: at (256,2) acc stays in VGPRs --
        //  R8 passed twice with this exact epilogue. Do not reuse at (256,4).)
        {
            const int rbase = lt * 64 + wave * 16 + quad * 4;
            unsigned short* Hrow =
                H + (size_t)(s_base[seg] + rbase) * D + (size_t)l16 * 8;
#pragma unroll
            for (int reg = 0; reg < 4; ++reg) {
                if (rbase + reg < s_cnt[seg]) {
                    u32x4 w;
#pragma unroll
                    for (int p = 0; p < 4; ++p) {
                        unsigned r;
                        asm("v_cvt_pk_bf16_f32 %0, %1, %2"
                            : "=v"(r)
                            : "v"(acc[2 * p][reg]), "v"(acc[2 * p + 1][reg]));
                        w[p] = r;
                    }
                    *(u32x4*)(Hrow + (size_t)reg * D) = w;
                }
            }
        }

        // rotate pipeline state
        if (haveN) {
            segA = segB; ltA = ltB;
#pragma unroll
            for (int kc = 0; kc < 4; ++kc) af[kc] = afn[kc];
        }
        if (haveN2) { segB = segC; ltB = ltC; nodeB = nodeC; }
    }
}

// ---------------------------------------------------------------------------
// Phase 2: one wave per dst node; dst made explicitly wave-uniform so
// pk2/bounds go through scalar loads; per-lane work = H load + 2 unpack +
// 2 FMA per edge. Per-(dst,rel) counts via wave-parallel ballot histogram
// (one coalesced pk2 vector load, 8 ballots -> packed 8-bit fields in two
// u32s; scalar fallback for degree > 64). 1/c via v_rcp (~1 ulp).
// H columns are permuted (see gemm_h): lane j's u32 holds cols
// c0 = 32*(j&3) + (j>>2) and c0+16 -> two dword stores at the end.
// ---------------------------------------------------------------------------
__global__ __launch_bounds__(256) void gather_out(
    const unsigned short* __restrict__ H, const unsigned* __restrict__ pk2,
    const int* __restrict__ tmpd, const int* __restrict__ offsd,
    float* __restrict__ out, int n_nodes)
{
    int dst = (blockIdx.x * 256 + threadIdx.x) >> 6;
    const int lane = threadIdx.x & 63;
    if (dst >= n_nodes) return;
    dst = __builtin_amdgcn_readfirstlane(dst);   // wave-uniform by construction

    const unsigned* HH = (const unsigned*)H;
    unsigned u0 = HH[(size_t)dst * 64 + lane];   // root+bias row
    float a0 = bf_lo(u0), a1 = bf_hi(u0);

    const int e0 = tmpd[dst] + offsd[dst >> 10];
    const int e1 = tmpd[dst + 1] + offsd[(dst + 1) >> 10];
    const int d  = e1 - e0;

    // per-rel counts (8x 8-bit fields in two u32s)
    unsigned acc0 = 0, acc1 = 0;
    if (d <= 64) {
        const bool valid = lane < d;
        unsigned p = valid ? pk2[e0 + lane] : 0u;
        unsigned r = (p >> 20) & 7u;
#pragma unroll
        for (int rr = 0; rr < 8; ++rr) {
            unsigned long long m = __ballot(valid && (r == (unsigned)rr));
            unsigned cnt = (unsigned)__popcll(m);
            if (rr < 4) acc0 |= cnt << (rr * 8);
            else        acc1 |= cnt << ((rr - 4) * 8);
        }
    } else {
        for (int e = e0; e < e1; ++e) {
            unsigned p = pk2[e];
            unsigned r = (p >> 20) & 7u;
            unsigned add = 1u << ((r & 3u) * 8u);
            if (r & 4u) acc1 += add; else acc0 += add;
        }
    }

    for (int base = e0; base < e1; base += 8) {
        float al[8];
        const unsigned* hp[8];
#pragma unroll
        for (int j = 0; j < 8; ++j) {
            int e = base + j;
            bool ok = (e < e1);
            unsigned p = ok ? pk2[e] : 0u;       // uniform address -> s_load
            unsigned r = (p >> 20) & 7u;
            unsigned cnt = (((r & 4u) ? acc1 : acc0) >> ((r & 3u) * 8u)) & 255u;
            al[j] = ok ? __builtin_amdgcn_rcpf((float)cnt) : 0.f;
            hp[j] = HH + (size_t)(p & 0xFFFFFu) * 64;
        }
        unsigned hv[8];
#pragma unroll
        for (int j = 0; j < 8; ++j) hv[j] = hp[j][lane];
#pragma unroll
        for (int j = 0; j < 8; ++j) {
            a0 += al[j] * bf_lo(hv[j]);
            a1 += al[j] * bf_hi(hv[j]);
        }
    }

    const int c0 = ((lane & 3) << 5) + (lane >> 2);
    float* orow = out + (size_t)dst * D;
    orow[c0]      = fmaxf(a0, 0.f);
    orow[c0 + 16] = fmaxf(a1, 0.f);
}

extern "C" void kernel_launch(void* const* d_in, const int* in_sizes, int n_in,
                              void* d_out, int out_size, void* d_ws, size_t ws_size,
                              hipStream_t stream) {
    const float* x          = (const float*)d_in[0];
    const int*   edge_index = (const int*)d_in[1];
    const int*   edge_type  = (const int*)d_in[2];
    const float* W          = (const float*)d_in[3];
    const float* root       = (const float*)d_in[4];
    const float* bias       = (const float*)d_in[5];
    float* out = (float*)d_out;

    const int n_nodes = in_sizes[0] / D;          // 100000 (assumed %4==0)
    const int n_edges = in_sizes[2];              // 600000
    const int n_rel   = in_sizes[3] / (D * D);    // 8
    const int nsegs   = n_rel + 1;
    const int nwords  = (n_rel * n_nodes) >> 2;   // 200000 (800KB byte flags)

    // ws layout (worst-case compact rows = n_rel*n_nodes)
    char* p = (char*)d_ws;
    auto alloc = [&](size_t bytes) {
        char* q = p; p += (bytes + 255) & ~(size_t)255; return q;
    };
    int* deg    = (int*)alloc((size_t)(n_nodes + 2) * 4);
    int* tmpd   = (int*)alloc((size_t)(n_nodes + 2) * 4);
    unsigned* flagsW = (unsigned*)alloc((size_t)nwords * 4);
    int* tmpw   = (int*)alloc((size_t)(nwords + 1) * 4);
    int* partsd = (int*)alloc(4096);
    int* partsw = (int*)alloc(4096);
    int* offsd  = (int*)alloc(4096);
    int* offsw  = (int*)alloc(4096);
    int* totw   = (int*)alloc(256);
    int* erank  = (int*)alloc((size_t)n_edges * 4);
    unsigned* pk2 = (unsigned*)alloc((size_t)n_edges * 4);
    unsigned* XB  = (unsigned*)alloc((size_t)n_nodes * (D / 2) * 4);
    unsigned short* WT = (unsigned short*)alloc((size_t)nsegs * D * D * 2);
    int* csrc   = (int*)alloc((size_t)n_edges * 4);
    unsigned short* H = (unsigned short*)p;       // worst (n_nodes + n_edges) rows

    const int nquads   = n_nodes * (D / 4);
    const int wt_total = nsegs * D * D;
    int conv_n = nquads;
    if (wt_total > conv_n) conv_n = wt_total;

    const int egrid = (n_edges + 255) / 256;
    const int conv_blocks = (conv_n + 255) / 256;
    const int nAd = (n_nodes + 1 + 1023) / 1024;  // 98
    const int nAw = (nwords + 1023) / 1024;       // 196

    int zero_n = n_nodes + 2;
    if (nwords > zero_n) zero_n = nwords;

    zero_ws<<<(zero_n + 255) / 256, 256, 0, stream>>>(
        deg, flagsW, n_nodes, nwords);
    prep_hist<<<egrid + conv_blocks, 256, 0, stream>>>(
        x, W, root, edge_index, edge_type, XB, WT, deg,
        (unsigned char*)flagsW, erank,
        nquads, wt_total, n_edges, n_nodes, n_rel, egrid);
    scanA2<<<nAd + nAw, 1024, 0, stream>>>(
        deg, flagsW, tmpd, partsd, tmpw, partsw, n_nodes + 1, nwords, nAd);
    scanB2<<<2, 1024, 0, stream>>>(partsd, partsw, offsd, offsw, totw, nAd, nAw);
    edge_bin<<<egrid, 256, 0, stream>>>(
        edge_index, edge_type, tmpd, offsd, tmpw, offsw, flagsW, erank,
        pk2, csrc, n_edges, n_nodes, n_rel);
    gemm_h<<<512, 256, 0, stream>>>(
        XB, WT, bias, csrc, tmpw, offsw, totw, H, n_nodes, n_rel);
    gather_out<<<(n_nodes + 3) / 4, 256, 0, stream>>>(
        H, pk2, tmpd, offsd, out, n_nodes);
}